// Round 6
// baseline (116.694 us; speedup 1.0000x reference)
//
#include <hip/hip_runtime.h>

#define NQ 9
#define NS 512            // 2^9 amplitudes
#define M2 1024           // [Re V; Im V] stacked rows
#define NSIMB 512         // sim blocks: 1 column each (512 threads = 8 waves)

// scoef float layout
#define ENT_H_BASE 0                          // 8 blocks x 4 local steps x 32
#define ROT_BASE   1024                       // 27 rots x 8
#define ROT3_BASE  1240                       // 3 x 128 merged 8x8 rot tables (build input)
#define ROT16_BASE 1624                       // 3 x 512 merged 16x16 SEL tables (bits 8..5)
#define M0123_BASE 3160                       // 8 x 256 entries x 2 (16x16 merged ent)
#define M78_BASE   7256                       // 8 x 64 entries x 2 (8x8 merged ent) = 1024 floats
#define COEF_FLOATS 8280                      // M78_BASE + 1024 (R5 bug: was 7768 -> OOB into slut)

typedef __attribute__((ext_vector_type(8))) short bf16x8;
typedef __attribute__((ext_vector_type(4))) float f32x4;

__device__ inline unsigned short f2bf(float f){
  unsigned int u = __float_as_uint(f);
  u += 0x7fffu + ((u >> 16) & 1u);   // round-to-nearest-even
  return (unsigned short)(u >> 16);
}

// =====================  8-wave, 1-amp-per-lane statevector sim  =====================
// Thread tid holds amp i = tid: bits 0-5 lane, bits 6-8 wave. Wire w <-> bit (8-w).
// Ent steps I0-I2 merged into one 16x16 op (bits 8..5); I7,I8 merged into one 8x8 op
// (bits 1,0,8). SEL layer: 16x16 op on bits 8..5 (rot3 x wire-3 rot) + 5 lane rots;
// CNOT rings folded into the NEXT exchange round's permuted write (sigma^-1 LUT).
// 19 exchange rounds total, strict A/B ping-pong, one __syncthreads each.

template<int LM>
__device__ inline float lxor(float v){
  if constexpr (LM == 1)
    return __int_as_float(__builtin_amdgcn_mov_dpp(__float_as_int(v), 0xB1, 0xF, 0xF, true));
  else if constexpr (LM == 2)
    return __int_as_float(__builtin_amdgcn_mov_dpp(__float_as_int(v), 0x4E, 0xF, 0xF, true));
  else if constexpr (LM == 3)
    return __int_as_float(__builtin_amdgcn_mov_dpp(__float_as_int(v), 0x1B, 0xF, 0xF, true));
  else if constexpr (LM < 32)
    return __int_as_float(__builtin_amdgcn_ds_swizzle(__float_as_int(v), (LM<<10)|0x1F));
  else
    return __shfl_xor(v, LM);
}

// fused 4x4 local step, both wires in lane bits -> pure cross-lane, no barrier
template<int CM, int TM>
__device__ inline void step_swz(float& ax, float& ay, int lane, const float* g){
  float tx = lxor<TM>(ax),      ty = lxor<TM>(ay);
  float cx = lxor<CM>(ax),      cy = lxor<CM>(ay);
  float bx = lxor<(CM^TM)>(ax), by = lxor<(CM^TM)>(ay);
  int p = ((lane & CM) ? 2 : 0) | ((lane & TM) ? 1 : 0);
  float4 hx = *(const float4*)(g + p*4);
  float4 hy = *(const float4*)(g + 16 + p*4);
  float ox = ax, oy = ay;
  ax = hx.x*ox - hy.x*oy + hx.y*tx - hy.y*ty
     + hx.z*cx - hy.z*cy + hx.w*bx - hy.w*by;
  ay = hx.x*oy + hy.x*ox + hx.y*ty + hy.y*tx
     + hx.z*cy + hy.z*cx + hx.w*by + hy.w*bx;
}

// merged 16x16 op on bits 8..5: one exchange round, 16 cmacs/amp.
// wi = LDS write index (== i normally; == sigma^-1(i) when a ring is folded in).
__device__ inline void mrg16(float& ax, float& ay, int i, int wi, float2* xb,
                             const float* Mt){
  xb[wi] = make_float2(ax, ay);
  __syncthreads();
  int p = (i >> 5) & 15;
  const float* Mr = Mt + p*32;
  int base = i & 31;
  float s0x=0.f,s0y=0.f,s1x=0.f,s1y=0.f;
  #pragma unroll
  for (int q = 0; q < 16; q += 2){
    float2 v0 = xb[(q<<5)|base];
    float2 v1 = xb[((q+1)<<5)|base];
    float m0x = Mr[q*2],   m0y = Mr[q*2+1];
    float m1x = Mr[q*2+2], m1y = Mr[q*2+3];
    s0x += m0x*v0.x - m0y*v0.y;  s0y += m0x*v0.y + m0y*v0.x;
    s1x += m1x*v1.x - m1y*v1.y;  s1y += m1x*v1.y + m1y*v1.x;
  }
  ax = s0x + s1x; ay = s0y + s1y;
}

// merged 8x8 op on bits (1,0,8): one exchange round, 8 cmacs/amp
__device__ inline void mrg8_78(float& ax, float& ay, int i, float2* xb, const float* Mt){
  xb[i] = make_float2(ax, ay);
  __syncthreads();
  int p = (((i>>1)&1)<<2) | ((i&1)<<1) | ((i>>8)&1);
  const float* Mr = Mt + p*16;
  int ib = i & 0x0FC;
  float s0x=0.f,s0y=0.f,s1x=0.f,s1y=0.f;
  #pragma unroll
  for (int q = 0; q < 8; q += 2){
    int j0 = ib | ((q>>2)<<1) | ((q>>1)&1);         // f=0
    float2 v0 = xb[j0];
    float2 v1 = xb[j0 | 0x100];                     // f=1
    float m0x = Mr[q*2],   m0y = Mr[q*2+1];
    float m1x = Mr[q*2+2], m1y = Mr[q*2+3];
    s0x += m0x*v0.x - m0y*v0.y;  s0y += m0x*v0.y + m0y*v0.x;
    s1x += m1x*v1.x - m1y*v1.y;  s1y += m1x*v1.y + m1y*v1.x;
  }
  ax = s0x + s1x; ay = s0y + s1y;
}

// Rot on a lane-bit wire
template<int LM>
__device__ inline void rot_swz(float& ax, float& ay, int lane, const float* u){
  float px = lxor<LM>(ax), py = lxor<LM>(ay);
  float4 uu = *(const float4*)(u + ((lane & LM) ? 4 : 0));
  float nx = uu.x*ax - uu.y*ay + uu.z*px - uu.w*py;
  float ny = uu.x*ay + uu.y*ax + uu.z*py + uu.w*px;
  ax = nx; ay = ny;
}

template<int I = 4>
__device__ inline void sel_lane_rots(float& ax, float& ay, int lane, const float* ub){
  rot_swz<(1<<(8-I))>(ax, ay, lane, ub + I*8);
  if constexpr (I < 8) sel_lane_rots<I+1>(ax, ay, lane, ub);
}

// ent block: merged I0-2 round (optional folded-ring permuted write), 4 local
// steps, merged I7-8 round
__device__ inline void entM(float& ax, float& ay, int i, int wi, int lane,
                            float2* bX, float2* bY, const float* scoef, int blk){
  mrg16(ax, ay, i, wi, bX, scoef + M0123_BASE + blk*512);
  step_swz<32,16>(ax, ay, lane, scoef + ENT_H_BASE + (blk*4+0)*32);   // I3
  step_swz<16, 8>(ax, ay, lane, scoef + ENT_H_BASE + (blk*4+1)*32);   // I4
  step_swz< 8, 4>(ax, ay, lane, scoef + ENT_H_BASE + (blk*4+2)*32);   // I5
  step_swz< 4, 2>(ax, ay, lane, scoef + ENT_H_BASE + (blk*4+3)*32);   // I6
  mrg8_78(ax, ay, i, bY, scoef + M78_BASE + blk*128);
}

// A2 layout (b128-friendly): ushort index = (c*1024 + row)*8 + sub,
// where column t = 8c + sub; row = amp (Re) or 512+amp (Im).

__global__ __launch_bounds__(512) void sim_prep(const float* __restrict__ params,
                                                const float* __restrict__ weights,
                                                const float* __restrict__ params2,
                                                const float* __restrict__ adds,
                                                unsigned short* __restrict__ A2,
                                                unsigned short* __restrict__ cT,
                                                float* __restrict__ out, int B){
  int tid = threadIdx.x;

  if (blockIdx.x >= NSIMB){
    // ---- prep path: build c (wave per sample) + zero the output accumulator ----
    int gid = (blockIdx.x - NSIMB) * 512 + tid;
    int b = gid >> 6;
    int lane = gid & 63;
    if (b < B){
      const float* ab = adds + b * NQ;
      float cw[NQ], sw[NQ];
      #pragma unroll
      for (int w = 0; w < NQ; ++w)
        __sincosf(0.5f * ab[w], &sw[w], &cw[w]);
      float p6 = 1.f;
      #pragma unroll
      for (int w = 0; w < 6; ++w)
        p6 *= ((lane >> (5 - w)) & 1) ? sw[w] : cw[w];
      union { unsigned short u[8]; uint4 v; } pk;
      #pragma unroll
      for (int j = 0; j < 8; ++j){
        float p = p6 * (((j>>2)&1) ? sw[6] : cw[6])
                     * (((j>>1)&1) ? sw[7] : cw[7])
                     * (( j    &1) ? sw[8] : cw[8]);
        pk.u[j] = f2bf(p);
      }
      *(uint4*)(cT + (size_t)b * NS + lane*8) = pk.v;
    }
    if (gid < B) out[gid] = 0.f;
    return;
  }

  // ---- sim path: one column, 8 waves, 1 amp/thread ----
  __shared__ float2 ebuf[1024];            // [0,512)=bufA, [512,1024)=bufB
  __shared__ float scoef[COEF_FLOATS];
  __shared__ unsigned short slut[3][512];  // sigma^-1 LUTs for rings 1..3
  float2* ebufA = ebuf;
  float2* ebufB = ebuf + 512;
  float* graw = (float*)ebuf;              // phase-1 scratch: raw G matrices

  // ---- phase 1: raw 4x4 gate matrices + small tables ----
  if (tid < 72){
    int blk = tid / 9, I = tid % 9;
    const float* p = (blk < 3) ? params + blk*36 : params2 + (blk-3)*36;
    float s0,c0,s1,c1,s2,c2,s3,c3;
    __sincosf(0.5f*p[4*I+0], &s0, &c0);
    __sincosf(0.5f*p[4*I+1], &s1, &c1);
    __sincosf(0.5f*p[4*I+2], &s2, &c2);
    __sincosf(0.5f*p[4*I+3], &s3, &c3);
    float m[4][4] = {
      { c0*c1, -c0*s1, -s0*c1,  s0*s1},
      { c0*s1,  c0*c1, -s0*s1, -s0*c1},
      { s0*c1, -s0*s1,  c0*c1, -c0*s1},
      { s0*s1,  s0*c1,  c0*s1,  c0*c1}};
    float gx[4][4], gy[4][4];
    #pragma unroll
    for (int q = 0; q < 4; ++q){
      gx[0][q] = m[1][q];  gy[0][q] = 0.f;      // row swap from X(q_target)
      gx[1][q] = m[0][q];  gy[1][q] = 0.f;
      gx[2][q] =  c3*c2*m[2][q] - s3*s2*m[3][q];
      gy[2][q] =  c3*s2*m[2][q] - s3*c2*m[3][q];
      gx[3][q] =  s3*s2*m[2][q] + c3*c2*m[3][q];
      gy[3][q] = -(s3*c2*m[2][q] + c3*s2*m[3][q]);
    }
    if (I >= 3 && I <= 6){
      // H-format for lane-local steps: H[p][d] = G[p][p^d]
      float* dst = scoef + ENT_H_BASE + (blk*4 + (I-3))*32;
      #pragma unroll
      for (int pp = 0; pp < 4; ++pp)
        #pragma unroll
        for (int d = 0; d < 4; ++d){
          dst[pp*4+d]    = gx[pp][pp^d];
          dst[16+pp*4+d] = gy[pp][pp^d];
        }
    } else {
      // raw G for merged tables
      float* dst = (I < 3) ? graw + (blk*3 + I)*32
                           : graw + 768 + (blk*2 + (I-7))*32;
      #pragma unroll
      for (int pp = 0; pp < 4; ++pp)
        #pragma unroll
        for (int q = 0; q < 4; ++q){
          dst[(pp*4+q)*2]   = gx[pp][q];
          dst[(pp*4+q)*2+1] = gy[pp][q];
        }
    }
  } else if (tid < 99){
    int r = tid - 72;
    int l = r / 9, i = r % 9;
    const float* w = weights + l*27 + 3*i;
    float phi = w[0], th = w[1], om = w[2];
    float sT,cT,sA,cA,sB,cB;
    __sincosf(0.5f*th, &sT, &cT);
    __sincosf(0.5f*(phi+om), &sA, &cA);
    __sincosf(0.5f*(om-phi), &sB, &cB);
    float* dst = scoef + ROT_BASE + r*8;
    dst[0] =  cA*cT;  dst[1] = -sA*cT;   // U00
    dst[2] = -cB*sT;  dst[3] =  sB*sT;   // U01
    dst[4] =  cA*cT;  dst[5] =  sA*cT;   // U11
    dst[6] =  cB*sT;  dst[7] =  sB*sT;   // U10
  } else if (tid < 123){
    // merged Rot(w0) x Rot(w1) x Rot(w2) tables: 24 threads = (layer l, row p)
    int idx = tid - 99;
    int l = idx >> 3, p = idx & 7;
    float e0x[3], e0y[3], e1x[3], e1y[3];
    #pragma unroll
    for (int w = 0; w < 3; ++w){
      const float* wp = weights + l*27 + 3*w;
      float phi = wp[0], th = wp[1], om = wp[2];
      float sT,cT,sA,cA,sB,cB;
      __sincosf(0.5f*th, &sT, &cT);
      __sincosf(0.5f*(phi+om), &sA, &cA);
      __sincosf(0.5f*(om-phi), &sB, &cB);
      int pw = (p >> (2 - w)) & 1;
      if (pw == 0){ e0x[w] =  cA*cT; e0y[w] = -sA*cT; e1x[w] = -cB*sT; e1y[w] =  sB*sT; }
      else        { e0x[w] =  cB*sT; e0y[w] =  sB*sT; e1x[w] =  cA*cT; e1y[w] =  sA*cT; }
    }
    float* dst = scoef + ROT3_BASE + l*128 + p*16;
    #pragma unroll
    for (int q = 0; q < 8; ++q){
      float rx = 1.f, ry = 0.f;
      #pragma unroll
      for (int w = 0; w < 3; ++w){
        int qw = (q >> (2 - w)) & 1;
        float fx = qw ? e1x[w] : e0x[w];
        float fy = qw ? e1y[w] : e0y[w];
        float nx = rx*fx - ry*fy;
        float ny = rx*fy + ry*fx;
        rx = nx; ry = ny;
      }
      dst[q*2]   = rx;
      dst[q*2+1] = ry;
    }
  }
  __syncthreads();

  // ---- phase 2: merged tables M0123 (16x16), M78 (8x8), ROT16, sigma LUTs ----
  {
    int blk = tid >> 6;
    const float* G0 = graw + (blk*3+0)*32;
    const float* G1 = graw + (blk*3+1)*32;
    const float* G2 = graw + (blk*3+2)*32;
    int e4 = (tid & 63) * 4;
    #pragma unroll
    for (int k = 0; k < 4; ++k){
      int e = e4 + k;
      int p = e >> 4, q = e & 15;
      int a=(p>>3)&1, b=(p>>2)&1, c=(p>>1)&1, d=p&1;
      int ee=(q>>3)&1, f=(q>>2)&1, g=(q>>1)&1, h=q&1;
      float sx = 0.f, sy = 0.f;
      #pragma unroll
      for (int m = 0; m < 2; ++m)
        #pragma unroll
        for (int n = 0; n < 2; ++n){
          const float* z2 = G2 + ((c*2+d)*4 + (n*2+h))*2;
          const float* z1 = G1 + ((b*2+n)*4 + (m*2+g))*2;
          const float* z0 = G0 + ((a*2+m)*4 + (ee*2+f))*2;
          float ux = z2[0]*z1[0] - z2[1]*z1[1];
          float uy = z2[0]*z1[1] + z2[1]*z1[0];
          float vx = ux*z0[0] - uy*z0[1];
          float vy = ux*z0[1] + uy*z0[0];
          sx += vx; sy += vy;
        }
      scoef[M0123_BASE + blk*512 + (p*16+q)*2]   = sx;
      scoef[M0123_BASE + blk*512 + (p*16+q)*2+1] = sy;
    }
    // M78: one entry per thread
    const float* G7 = graw + 768 + (blk*2+0)*32;
    const float* G8 = graw + 768 + (blk*2+1)*32;
    int e = tid & 63;
    int p = e >> 3, q = e & 7;
    int a=(p>>2)&1, b=(p>>1)&1, c=p&1;    // out (b1,b0,b8)
    int d=(q>>2)&1, ei=(q>>1)&1, f=q&1;   // in  (b1,b0,b8)
    float sx = 0.f, sy = 0.f;
    #pragma unroll
    for (int m = 0; m < 2; ++m){
      const float* z8 = G8 + ((b*2+c)*4 + (m*2+f))*2;
      const float* z7 = G7 + ((a*2+m)*4 + (d*2+ei))*2;
      sx += z8[0]*z7[0] - z8[1]*z7[1];
      sy += z8[0]*z7[1] + z8[1]*z7[0];
    }
    scoef[M78_BASE + blk*128 + (p*8+q)*2]   = sx;
    scoef[M78_BASE + blk*128 + (p*8+q)*2+1] = sy;

    // ROT16: rot3 (bits 8,7,6) x wire-3 rot (bit 5) -> 16x16, 768 entries
    for (int e2 = tid; e2 < 768; e2 += 512){
      int l = e2 >> 8, pq = e2 & 255;
      int pp = pq >> 4, qq = pq & 15;
      const float* R3 = scoef + ROT3_BASE + l*128 + (pp>>1)*16 + (qq>>1)*2;
      const float* U = scoef + ROT_BASE + (l*9+3)*8;
      int pb = pp & 1, qb = qq & 1;
      float ux, uy;
      if (pb == 0){ if (qb == 0){ ux=U[0]; uy=U[1]; } else { ux=U[2]; uy=U[3]; } }
      else        { if (qb == 1){ ux=U[4]; uy=U[5]; } else { ux=U[6]; uy=U[7]; } }
      float rx = R3[0], ry = R3[1];
      scoef[ROT16_BASE + l*512 + pp*32 + qq*2]   = rx*ux - ry*uy;
      scoef[ROT16_BASE + l*512 + pp*32 + qq*2+1] = rx*uy + ry*ux;
    }

    // sigma^-1 LUTs: slut[R-1][sigma(t)] = t  (ring permutation inversion)
    for (int R = 1; R <= 3; ++R){
      int s = tid;
      for (int k = 8; k >= 0; --k){
        int bc = 8 - k;
        int it = k + R; if (it >= 9) it -= 9;
        int bt = 8 - it;
        s ^= ((s >> bc) & 1) << bt;
      }
      slut[R-1][s] = (unsigned short)tid;
    }
  }
  __syncthreads();

  // ---- sim ----
  int i = tid, lane = tid & 63;
  int col = blockIdx.x;
  int w1 = slut[0][i], w2 = slut[1][i], w3 = slut[2][i];  // permuted write idxs
  float ax, ay;
  int pc = __popc((unsigned)col) & 3;
  float prx = (pc==0) ? 1.f : (pc==2 ? -1.f : 0.f);
  float pry = (pc==3) ? 1.f : (pc==1 ? -1.f : 0.f);
  ax = (i == col) ? prx : 0.f;
  ay = (i == col) ? pry : 0.f;

  // rounds 1-6: ent blocks 0-2 (A,B per block)
  #pragma unroll 1
  for (int blk = 0; blk < 3; ++blk)
    entM(ax, ay, i, i, lane, ebufA, ebufB, scoef, blk);

  // rounds 7-9: SEL layers (16x16 incl. wire-3 rot; rings folded into next write)
  mrg16(ax, ay, i, i,  ebufA, scoef + ROT16_BASE + 0*512);
  sel_lane_rots<4>(ax, ay, lane, scoef + ROT_BASE + 0*72);
  mrg16(ax, ay, i, w1, ebufB, scoef + ROT16_BASE + 1*512);   // ring1 folded
  sel_lane_rots<4>(ax, ay, lane, scoef + ROT_BASE + 1*72);
  mrg16(ax, ay, i, w2, ebufA, scoef + ROT16_BASE + 2*512);   // ring2 folded
  sel_lane_rots<4>(ax, ay, lane, scoef + ROT_BASE + 2*72);

  // rounds 10-11: ent block 3 (ring3 folded into its first write; B,A)
  entM(ax, ay, i, w3, lane, ebufB, ebufA, scoef, 3);
  // rounds 12-19: ent blocks 4-7 (B,A per block)
  #pragma unroll 1
  for (int blk = 4; blk < 8; ++blk)
    entM(ax, ay, i, i, lane, ebufB, ebufA, scoef, blk);

  // ---- direct A2 stores: thread owns Re+Im of its amp ----
  int c = col >> 3, sub = col & 7;
  size_t base = (size_t)c * 1024;
  A2[(base + i)*8 + sub]       = f2bf(ax);   // Re row i
  A2[(base + 512 + i)*8 + sub] = f2bf(ay);   // Im row 512+i
}

// Phi2 = A2(1024x512) @ c(512xB); out[b] = sum_row sign(row) * Phi2[row][b]^2,
// sign(row) = -1 iff (row & 256). A2: 16B at (c*1024+row)*16 = k=8c..8c+7 of row.
// 512 threads = 8 waves (2 row-groups x 4 col-groups) per 128x128 tile.
__global__ __launch_bounds__(512) void gemm_out(const unsigned short* __restrict__ A2,
                                                const unsigned short* __restrict__ cT,
                                                float* __restrict__ out){
  int bx = blockIdx.x;            // N tile (128 cols of b)
  int by = blockIdx.y;            // M tile (128 rows), 8 tiles
  int tid = threadIdx.x;
  int wave = tid >> 6, lane = tid & 63;
  int wy = wave >> 2, wx = wave & 3;
  int lane15 = lane & 15, quad = lane >> 4;
  int rowBase = by*128 + wy*64;
  int colBase = bx*128 + wx*32;
  const bf16x8* Ap8 = (const bf16x8*)A2;   // 16B units: (c*1024 + row)
  const short* Bp = (const short*)cT;      // [col][k]

  f32x4 acc[4][2];
  #pragma unroll
  for (int i = 0; i < 4; ++i)
    #pragma unroll
    for (int j = 0; j < 2; ++j)
      acc[i][j] = (f32x4){0.f, 0.f, 0.f, 0.f};

  #pragma unroll 4
  for (int k0 = 0; k0 < NS; k0 += 32){
    bf16x8 a[4], b[2];
    int c = (k0 >> 3) + quad;
    #pragma unroll
    for (int mi = 0; mi < 4; ++mi)
      a[mi] = Ap8[(size_t)c*1024 + rowBase + mi*16 + lane15];
    #pragma unroll
    for (int ni = 0; ni < 2; ++ni)
      b[ni] = *(const bf16x8*)(Bp + (size_t)(colBase + ni*16 + lane15)*NS + k0 + quad*8);
    #pragma unroll
    for (int mi = 0; mi < 4; ++mi)
      #pragma unroll
      for (int ni = 0; ni < 2; ++ni)
        acc[mi][ni] = __builtin_amdgcn_mfma_f32_16x16x32_bf16(a[mi], b[ni], acc[mi][ni], 0, 0, 0);
  }

  float sign = (by & 2) ? -1.f : 1.f;
  #pragma unroll
  for (int ni = 0; ni < 2; ++ni){
    float cs = 0.f;
    #pragma unroll
    for (int mi = 0; mi < 4; ++mi)
      #pragma unroll
      for (int r = 0; r < 4; ++r)
        cs += acc[mi][ni][r] * acc[mi][ni][r];
    cs += __shfl_xor(cs, 16);
    cs += __shfl_xor(cs, 32);
    if (quad == 0)
      atomicAdd(out + colBase + ni*16 + lane15, sign * cs);
  }
}

extern "C" void kernel_launch(void* const* d_in, const int* in_sizes, int n_in,
                              void* d_out, int out_size, void* d_ws, size_t ws_size,
                              hipStream_t stream) {
  const float* adds    = (const float*)d_in[0];
  const float* params  = (const float*)d_in[1];
  const float* weights = (const float*)d_in[2];
  const float* params2 = (const float*)d_in[3];
  float* out = (float*)d_out;
  int B = in_sizes[0] / NQ;   // 8192

  unsigned short* A2 = (unsigned short*)d_ws;        // 1024*512 bf16 = 1 MB (c-blocked)
  unsigned short* cT = A2 + (size_t)M2 * NS;         // B*512 bf16 = 8 MB

  int prepBlocks = (B * 64 + 511) / 512;             // 1024
  hipLaunchKernelGGL(sim_prep, dim3(NSIMB + prepBlocks), dim3(512), 0, stream,
                     params, weights, params2, adds, A2, cT, out, B);
  hipLaunchKernelGGL(gemm_out, dim3(B / 128, 8), dim3(512), 0, stream, A2, cT, out);
}

// Round 7
// 113.472 us; speedup vs baseline: 1.0284x; 1.0284x over previous
//
#include <hip/hip_runtime.h>

#define NQ 9
#define NS 512            // 2^9 amplitudes
#define M2 1024           // [Re V; Im V] stacked rows
#define NSIMB 256         // sim blocks: 2 columns each (512 threads = 8 waves)

// scoef float layout
#define ENT_H_BASE 0                          // 8 blocks x 4 local steps x 32
#define ROT_BASE   1024                       // 27 rots x 8
#define ROT3_BASE  1240                       // 3 x 128 merged 8x8 rot tables (build input)
#define ROT16_BASE 1624                       // 3 x 512 merged 16x16 SEL tables (bits 8..5)
#define M0123_BASE 3160                       // 8 x 256 entries x 2 (16x16 merged ent)
#define M78_BASE   7256                       // 8 x 64 entries x 2 (8x8 merged ent) = 1024 floats
#define COEF_FLOATS 8280                      // M78_BASE + 1024

typedef __attribute__((ext_vector_type(8))) short bf16x8;
typedef __attribute__((ext_vector_type(4))) float f32x4;

__device__ inline unsigned short f2bf(float f){
  unsigned int u = __float_as_uint(f);
  u += 0x7fffu + ((u >> 16) & 1u);   // round-to-nearest-even
  return (unsigned short)(u >> 16);
}

// =====================  8-wave, 2-columns-per-thread statevector sim  =====================
// Thread tid holds amp i = tid of TWO independent columns (2*bx, 2*bx+1).
// Bits 0-5 lane, 6-8 wave. Wire w <-> bit (8-w). 19 exchange rounds, strict A/B
// ping-pong; per round both columns exchange (barrier cost amortized 2x, coef
// loads shared, LDS reads 2-way ILP).

template<int LM>
__device__ inline float lxor(float v){
  if constexpr (LM == 1)
    return __int_as_float(__builtin_amdgcn_mov_dpp(__float_as_int(v), 0xB1, 0xF, 0xF, true));
  else if constexpr (LM == 2)
    return __int_as_float(__builtin_amdgcn_mov_dpp(__float_as_int(v), 0x4E, 0xF, 0xF, true));
  else if constexpr (LM == 3)
    return __int_as_float(__builtin_amdgcn_mov_dpp(__float_as_int(v), 0x1B, 0xF, 0xF, true));
  else if constexpr (LM < 32)
    return __int_as_float(__builtin_amdgcn_ds_swizzle(__float_as_int(v), (LM<<10)|0x1F));
  else
    return __shfl_xor(v, LM);
}

// fused 4x4 local step on lane bits, both columns, shared coefs
template<int CM, int TM>
__device__ inline void step_swz2(float& a0x, float& a0y, float& a1x, float& a1y,
                                 int lane, const float* g){
  float t0x = lxor<TM>(a0x),      t0y = lxor<TM>(a0y);
  float c0x = lxor<CM>(a0x),      c0y = lxor<CM>(a0y);
  float b0x = lxor<(CM^TM)>(a0x), b0y = lxor<(CM^TM)>(a0y);
  float t1x = lxor<TM>(a1x),      t1y = lxor<TM>(a1y);
  float c1x = lxor<CM>(a1x),      c1y = lxor<CM>(a1y);
  float b1x = lxor<(CM^TM)>(a1x), b1y = lxor<(CM^TM)>(a1y);
  int p = ((lane & CM) ? 2 : 0) | ((lane & TM) ? 1 : 0);
  float4 hx = *(const float4*)(g + p*4);
  float4 hy = *(const float4*)(g + 16 + p*4);
  float o0x = a0x, o0y = a0y, o1x = a1x, o1y = a1y;
  a0x = hx.x*o0x - hy.x*o0y + hx.y*t0x - hy.y*t0y
      + hx.z*c0x - hy.z*c0y + hx.w*b0x - hy.w*b0y;
  a0y = hx.x*o0y + hy.x*o0x + hx.y*t0y + hy.y*t0x
      + hx.z*c0y + hy.z*c0x + hx.w*b0y + hy.w*b0x;
  a1x = hx.x*o1x - hy.x*o1y + hx.y*t1x - hy.y*t1y
      + hx.z*c1x - hy.z*c1y + hx.w*b1x - hy.w*b1y;
  a1y = hx.x*o1y + hy.x*o1x + hx.y*t1y + hy.y*t1x
      + hx.z*c1y + hy.z*c1x + hx.w*b1y + hy.w*b1x;
}

// merged 16x16 op on bits 8..5, both columns: one exchange round.
// xb = [2][512] buffer; wi = write index (sigma^-1(i) when a ring is folded).
__device__ inline void mrg16_2(float& a0x, float& a0y, float& a1x, float& a1y,
                               int i, int wi, float2* xb, const float* Mt){
  xb[wi]       = make_float2(a0x, a0y);
  xb[512 + wi] = make_float2(a1x, a1y);
  __syncthreads();
  int p = (i >> 5) & 15;
  const float* Mr = Mt + p*32;
  int base = i & 31;
  float s0x=0.f,s0y=0.f,s1x=0.f,s1y=0.f;
  #pragma unroll
  for (int q = 0; q < 16; ++q){
    float mx = Mr[q*2], my = Mr[q*2+1];
    float2 v0 = xb[(q<<5)|base];
    float2 v1 = xb[512 + ((q<<5)|base)];
    s0x += mx*v0.x - my*v0.y;  s0y += mx*v0.y + my*v0.x;
    s1x += mx*v1.x - my*v1.y;  s1y += mx*v1.y + my*v1.x;
  }
  a0x = s0x; a0y = s0y; a1x = s1x; a1y = s1y;
}

// merged 8x8 op on bits (1,0,8), both columns: one exchange round
__device__ inline void mrg8_2(float& a0x, float& a0y, float& a1x, float& a1y,
                              int i, float2* xb, const float* Mt){
  xb[i]       = make_float2(a0x, a0y);
  xb[512 + i] = make_float2(a1x, a1y);
  __syncthreads();
  int p = (((i>>1)&1)<<2) | ((i&1)<<1) | ((i>>8)&1);
  const float* Mr = Mt + p*16;
  int ib = i & 0x0FC;
  float s0x=0.f,s0y=0.f,s1x=0.f,s1y=0.f;
  #pragma unroll
  for (int q = 0; q < 8; ++q){
    int j = (ib | (((q>>1)&3) ^ (((q>>1)&3) & 0)) ) ;  // placeholder, fixed below
    (void)j;
    int j0 = ib | (((q>>2)&1)<<1) | ((q>>1)&1);
    int jj = (q & 1) ? (j0 | 0x100) : j0;
    float mx = Mr[q*2], my = Mr[q*2+1];
    float2 v0 = xb[jj];
    float2 v1 = xb[512 + jj];
    s0x += mx*v0.x - my*v0.y;  s0y += mx*v0.y + my*v0.x;
    s1x += mx*v1.x - my*v1.y;  s1y += mx*v1.y + my*v1.x;
  }
  a0x = s0x; a0y = s0y; a1x = s1x; a1y = s1y;
}

// Rot on a lane-bit wire, both columns, shared coefs
template<int LM>
__device__ inline void rot_swz2(float& a0x, float& a0y, float& a1x, float& a1y,
                                int lane, const float* u){
  float4 uu = *(const float4*)(u + ((lane & LM) ? 4 : 0));
  float p0x = lxor<LM>(a0x), p0y = lxor<LM>(a0y);
  float p1x = lxor<LM>(a1x), p1y = lxor<LM>(a1y);
  float n0x = uu.x*a0x - uu.y*a0y + uu.z*p0x - uu.w*p0y;
  float n0y = uu.x*a0y + uu.y*a0x + uu.z*p0y + uu.w*p0x;
  float n1x = uu.x*a1x - uu.y*a1y + uu.z*p1x - uu.w*p1y;
  float n1y = uu.x*a1y + uu.y*a1x + uu.z*p1y + uu.w*p1x;
  a0x = n0x; a0y = n0y; a1x = n1x; a1y = n1y;
}

template<int I = 4>
__device__ inline void sel_lane_rots2(float& a0x, float& a0y, float& a1x, float& a1y,
                                      int lane, const float* ub){
  rot_swz2<(1<<(8-I))>(a0x, a0y, a1x, a1y, lane, ub + I*8);
  if constexpr (I < 8) sel_lane_rots2<I+1>(a0x, a0y, a1x, a1y, lane, ub);
}

// ent block: merged I0-2 round (optional folded-ring permuted write), 4 local
// steps, merged I7-8 round
__device__ inline void entM2(float& a0x, float& a0y, float& a1x, float& a1y,
                             int i, int wi, int lane,
                             float2* bX, float2* bY, const float* scoef, int blk){
  mrg16_2(a0x, a0y, a1x, a1y, i, wi, bX, scoef + M0123_BASE + blk*512);
  step_swz2<32,16>(a0x, a0y, a1x, a1y, lane, scoef + ENT_H_BASE + (blk*4+0)*32);  // I3
  step_swz2<16, 8>(a0x, a0y, a1x, a1y, lane, scoef + ENT_H_BASE + (blk*4+1)*32);  // I4
  step_swz2< 8, 4>(a0x, a0y, a1x, a1y, lane, scoef + ENT_H_BASE + (blk*4+2)*32);  // I5
  step_swz2< 4, 2>(a0x, a0y, a1x, a1y, lane, scoef + ENT_H_BASE + (blk*4+3)*32);  // I6
  mrg8_2(a0x, a0y, a1x, a1y, i, bY, scoef + M78_BASE + blk*128);
}

// A2 layout (b128-friendly): ushort index = (c*1024 + row)*8 + sub,
// where column t = 8c + sub; row = amp (Re) or 512+amp (Im).

__global__ __launch_bounds__(512) void sim_prep(const float* __restrict__ params,
                                                const float* __restrict__ weights,
                                                const float* __restrict__ params2,
                                                const float* __restrict__ adds,
                                                unsigned short* __restrict__ A2,
                                                unsigned short* __restrict__ cT,
                                                float* __restrict__ out, int B){
  int tid = threadIdx.x;

  if (blockIdx.x >= NSIMB){
    // ---- prep path: build c (wave per sample) + zero the output accumulator ----
    int gid = (blockIdx.x - NSIMB) * 512 + tid;
    int b = gid >> 6;
    int lane = gid & 63;
    if (b < B){
      const float* ab = adds + b * NQ;
      float cw[NQ], sw[NQ];
      #pragma unroll
      for (int w = 0; w < NQ; ++w)
        __sincosf(0.5f * ab[w], &sw[w], &cw[w]);
      float p6 = 1.f;
      #pragma unroll
      for (int w = 0; w < 6; ++w)
        p6 *= ((lane >> (5 - w)) & 1) ? sw[w] : cw[w];
      union { unsigned short u[8]; uint4 v; } pk;
      #pragma unroll
      for (int j = 0; j < 8; ++j){
        float p = p6 * (((j>>2)&1) ? sw[6] : cw[6])
                     * (((j>>1)&1) ? sw[7] : cw[7])
                     * (( j    &1) ? sw[8] : cw[8]);
        pk.u[j] = f2bf(p);
      }
      *(uint4*)(cT + (size_t)b * NS + lane*8) = pk.v;
    }
    if (gid < B) out[gid] = 0.f;
    return;
  }

  // ---- sim path: two columns, 8 waves, 1 amp/thread/column ----
  __shared__ float2 ebufA[1024];           // [col][512], ping
  __shared__ float2 ebufB[1024];           // [col][512], pong
  __shared__ float scoef[COEF_FLOATS];
  __shared__ unsigned short slut[3][512];  // sigma^-1 LUTs for rings 1..3
  float* graw = (float*)ebufA;             // phase-1 scratch: raw G matrices (<=1280 floats)

  // ---- phase 1: raw 4x4 gate matrices + small tables ----
  if (tid < 72){
    int blk = tid / 9, I = tid % 9;
    const float* p = (blk < 3) ? params + blk*36 : params2 + (blk-3)*36;
    float s0,c0,s1,c1,s2,c2,s3,c3;
    __sincosf(0.5f*p[4*I+0], &s0, &c0);
    __sincosf(0.5f*p[4*I+1], &s1, &c1);
    __sincosf(0.5f*p[4*I+2], &s2, &c2);
    __sincosf(0.5f*p[4*I+3], &s3, &c3);
    float m[4][4] = {
      { c0*c1, -c0*s1, -s0*c1,  s0*s1},
      { c0*s1,  c0*c1, -s0*s1, -s0*c1},
      { s0*c1, -s0*s1,  c0*c1, -c0*s1},
      { s0*s1,  s0*c1,  c0*s1,  c0*c1}};
    float gx[4][4], gy[4][4];
    #pragma unroll
    for (int q = 0; q < 4; ++q){
      gx[0][q] = m[1][q];  gy[0][q] = 0.f;      // row swap from X(q_target)
      gx[1][q] = m[0][q];  gy[1][q] = 0.f;
      gx[2][q] =  c3*c2*m[2][q] - s3*s2*m[3][q];
      gy[2][q] =  c3*s2*m[2][q] - s3*c2*m[3][q];
      gx[3][q] =  s3*s2*m[2][q] + c3*c2*m[3][q];
      gy[3][q] = -(s3*c2*m[2][q] + c3*s2*m[3][q]);
    }
    if (I >= 3 && I <= 6){
      // H-format for lane-local steps: H[p][d] = G[p][p^d]
      float* dst = scoef + ENT_H_BASE + (blk*4 + (I-3))*32;
      #pragma unroll
      for (int pp = 0; pp < 4; ++pp)
        #pragma unroll
        for (int d = 0; d < 4; ++d){
          dst[pp*4+d]    = gx[pp][pp^d];
          dst[16+pp*4+d] = gy[pp][pp^d];
        }
    } else {
      // raw G for merged tables
      float* dst = (I < 3) ? graw + (blk*3 + I)*32
                           : graw + 768 + (blk*2 + (I-7))*32;
      #pragma unroll
      for (int pp = 0; pp < 4; ++pp)
        #pragma unroll
        for (int q = 0; q < 4; ++q){
          dst[(pp*4+q)*2]   = gx[pp][q];
          dst[(pp*4+q)*2+1] = gy[pp][q];
        }
    }
  } else if (tid < 99){
    int r = tid - 72;
    int l = r / 9, i = r % 9;
    const float* w = weights + l*27 + 3*i;
    float phi = w[0], th = w[1], om = w[2];
    float sT,cT,sA,cA,sB,cB;
    __sincosf(0.5f*th, &sT, &cT);
    __sincosf(0.5f*(phi+om), &sA, &cA);
    __sincosf(0.5f*(om-phi), &sB, &cB);
    float* dst = scoef + ROT_BASE + r*8;
    dst[0] =  cA*cT;  dst[1] = -sA*cT;   // U00
    dst[2] = -cB*sT;  dst[3] =  sB*sT;   // U01
    dst[4] =  cA*cT;  dst[5] =  sA*cT;   // U11
    dst[6] =  cB*sT;  dst[7] =  sB*sT;   // U10
  } else if (tid < 123){
    // merged Rot(w0) x Rot(w1) x Rot(w2) tables: 24 threads = (layer l, row p)
    int idx = tid - 99;
    int l = idx >> 3, p = idx & 7;
    float e0x[3], e0y[3], e1x[3], e1y[3];
    #pragma unroll
    for (int w = 0; w < 3; ++w){
      const float* wp = weights + l*27 + 3*w;
      float phi = wp[0], th = wp[1], om = wp[2];
      float sT,cT,sA,cA,sB,cB;
      __sincosf(0.5f*th, &sT, &cT);
      __sincosf(0.5f*(phi+om), &sA, &cA);
      __sincosf(0.5f*(om-phi), &sB, &cB);
      int pw = (p >> (2 - w)) & 1;
      if (pw == 0){ e0x[w] =  cA*cT; e0y[w] = -sA*cT; e1x[w] = -cB*sT; e1y[w] =  sB*sT; }
      else        { e0x[w] =  cB*sT; e0y[w] =  sB*sT; e1x[w] =  cA*cT; e1y[w] =  sA*cT; }
    }
    float* dst = scoef + ROT3_BASE + l*128 + p*16;
    #pragma unroll
    for (int q = 0; q < 8; ++q){
      float rx = 1.f, ry = 0.f;
      #pragma unroll
      for (int w = 0; w < 3; ++w){
        int qw = (q >> (2 - w)) & 1;
        float fx = qw ? e1x[w] : e0x[w];
        float fy = qw ? e1y[w] : e0y[w];
        float nx = rx*fx - ry*fy;
        float ny = rx*fy + ry*fx;
        rx = nx; ry = ny;
      }
      dst[q*2]   = rx;
      dst[q*2+1] = ry;
    }
  }
  __syncthreads();

  // ---- phase 2: merged tables M0123 (16x16), M78 (8x8), ROT16, sigma LUTs ----
  {
    int blk = tid >> 6;
    const float* G0 = graw + (blk*3+0)*32;
    const float* G1 = graw + (blk*3+1)*32;
    const float* G2 = graw + (blk*3+2)*32;
    int e4 = (tid & 63) * 4;
    #pragma unroll
    for (int k = 0; k < 4; ++k){
      int e = e4 + k;
      int p = e >> 4, q = e & 15;
      int a=(p>>3)&1, b=(p>>2)&1, c=(p>>1)&1, d=p&1;
      int ee=(q>>3)&1, f=(q>>2)&1, g=(q>>1)&1, h=q&1;
      float sx = 0.f, sy = 0.f;
      #pragma unroll
      for (int m = 0; m < 2; ++m)
        #pragma unroll
        for (int n = 0; n < 2; ++n){
          const float* z2 = G2 + ((c*2+d)*4 + (n*2+h))*2;
          const float* z1 = G1 + ((b*2+n)*4 + (m*2+g))*2;
          const float* z0 = G0 + ((a*2+m)*4 + (ee*2+f))*2;
          float ux = z2[0]*z1[0] - z2[1]*z1[1];
          float uy = z2[0]*z1[1] + z2[1]*z1[0];
          float vx = ux*z0[0] - uy*z0[1];
          float vy = ux*z0[1] + uy*z0[0];
          sx += vx; sy += vy;
        }
      scoef[M0123_BASE + blk*512 + (p*16+q)*2]   = sx;
      scoef[M0123_BASE + blk*512 + (p*16+q)*2+1] = sy;
    }
    // M78: one entry per thread
    const float* G7 = graw + 768 + (blk*2+0)*32;
    const float* G8 = graw + 768 + (blk*2+1)*32;
    int e = tid & 63;
    int p = e >> 3, q = e & 7;
    int a=(p>>2)&1, b=(p>>1)&1, c=p&1;    // out (b1,b0,b8)
    int d=(q>>2)&1, ei=(q>>1)&1, f=q&1;   // in  (b1,b0,b8)
    float sx = 0.f, sy = 0.f;
    #pragma unroll
    for (int m = 0; m < 2; ++m){
      const float* z8 = G8 + ((b*2+c)*4 + (m*2+f))*2;
      const float* z7 = G7 + ((a*2+m)*4 + (d*2+ei))*2;
      sx += z8[0]*z7[0] - z8[1]*z7[1];
      sy += z8[0]*z7[1] + z8[1]*z7[0];
    }
    scoef[M78_BASE + blk*128 + (p*8+q)*2]   = sx;
    scoef[M78_BASE + blk*128 + (p*8+q)*2+1] = sy;

    // ROT16: rot3 (bits 8,7,6) x wire-3 rot (bit 5) -> 16x16, 768 entries
    for (int e2 = tid; e2 < 768; e2 += 512){
      int l = e2 >> 8, pq = e2 & 255;
      int pp = pq >> 4, qq = pq & 15;
      const float* R3 = scoef + ROT3_BASE + l*128 + (pp>>1)*16 + (qq>>1)*2;
      const float* U = scoef + ROT_BASE + (l*9+3)*8;
      int pb = pp & 1, qb = qq & 1;
      float ux, uy;
      if (pb == 0){ if (qb == 0){ ux=U[0]; uy=U[1]; } else { ux=U[2]; uy=U[3]; } }
      else        { if (qb == 1){ ux=U[4]; uy=U[5]; } else { ux=U[6]; uy=U[7]; } }
      float rx = R3[0], ry = R3[1];
      scoef[ROT16_BASE + l*512 + pp*32 + qq*2]   = rx*ux - ry*uy;
      scoef[ROT16_BASE + l*512 + pp*32 + qq*2+1] = rx*uy + ry*ux;
    }

    // sigma^-1 LUTs: slut[R-1][sigma(t)] = t  (ring permutation inversion)
    for (int R = 1; R <= 3; ++R){
      int s = tid;
      for (int k = 8; k >= 0; --k){
        int bc = 8 - k;
        int it = k + R; if (it >= 9) it -= 9;
        int bt = 8 - it;
        s ^= ((s >> bc) & 1) << bt;
      }
      slut[R-1][s] = (unsigned short)tid;
    }
  }
  __syncthreads();

  // ---- sim: columns c0 = 2*bx, c1 = 2*bx+1 ----
  int i = tid, lane = tid & 63;
  int c0 = blockIdx.x * 2, c1 = c0 + 1;
  int w1 = slut[0][i], w2 = slut[1][i], w3 = slut[2][i];  // permuted write idxs
  float a0x, a0y, a1x, a1y;
  {
    int pc0 = __popc((unsigned)c0) & 3;
    int pc1 = __popc((unsigned)c1) & 3;
    float prx0 = (pc0==0) ? 1.f : (pc0==2 ? -1.f : 0.f);
    float pry0 = (pc0==3) ? 1.f : (pc0==1 ? -1.f : 0.f);
    float prx1 = (pc1==0) ? 1.f : (pc1==2 ? -1.f : 0.f);
    float pry1 = (pc1==3) ? 1.f : (pc1==1 ? -1.f : 0.f);
    a0x = (i == c0) ? prx0 : 0.f;
    a0y = (i == c0) ? pry0 : 0.f;
    a1x = (i == c1) ? prx1 : 0.f;
    a1y = (i == c1) ? pry1 : 0.f;
  }

  // rounds 1-6: ent blocks 0-2 (A,B per block)
  #pragma unroll 1
  for (int blk = 0; blk < 3; ++blk)
    entM2(a0x, a0y, a1x, a1y, i, i, lane, ebufA, ebufB, scoef, blk);

  // rounds 7-9: SEL layers (16x16 incl. wire-3 rot; rings folded into next write)
  mrg16_2(a0x, a0y, a1x, a1y, i, i,  ebufA, scoef + ROT16_BASE + 0*512);
  sel_lane_rots2<4>(a0x, a0y, a1x, a1y, lane, scoef + ROT_BASE + 0*72);
  mrg16_2(a0x, a0y, a1x, a1y, i, w1, ebufB, scoef + ROT16_BASE + 1*512);  // ring1 folded
  sel_lane_rots2<4>(a0x, a0y, a1x, a1y, lane, scoef + ROT_BASE + 1*72);
  mrg16_2(a0x, a0y, a1x, a1y, i, w2, ebufA, scoef + ROT16_BASE + 2*512);  // ring2 folded
  sel_lane_rots2<4>(a0x, a0y, a1x, a1y, lane, scoef + ROT_BASE + 2*72);

  // rounds 10-11: ent block 3 (ring3 folded into its first write; B,A)
  entM2(a0x, a0y, a1x, a1y, i, w3, lane, ebufB, ebufA, scoef, 3);
  // rounds 12-19: ent blocks 4-7 (B,A per block)
  #pragma unroll 1
  for (int blk = 4; blk < 8; ++blk)
    entM2(a0x, a0y, a1x, a1y, i, i, lane, ebufB, ebufA, scoef, blk);

  // ---- direct A2 stores: packed u32 holds both columns (adjacent subs) ----
  int c = c0 >> 3;                       // = bx >> 2
  int jp = blockIdx.x & 3;               // (c0 & 7) / 2
  size_t base = (size_t)c * 1024;
  unsigned int* Aw = (unsigned int*)A2;
  unsigned int re = (unsigned)f2bf(a0x) | ((unsigned)f2bf(a1x) << 16);
  unsigned int im = (unsigned)f2bf(a0y) | ((unsigned)f2bf(a1y) << 16);
  Aw[(base + i)*4 + jp]       = re;      // Re row i
  Aw[(base + 512 + i)*4 + jp] = im;      // Im row 512+i
}

// Phi2 = A2(1024x512) @ c(512xB); out[b] = sum_row sign(row) * Phi2[row][b]^2,
// sign(row) = -1 iff (row & 256). A2: 16B at (c*1024+row)*16 = k=8c..8c+7 of row.
__global__ __launch_bounds__(256) void gemm_out(const unsigned short* __restrict__ A2,
                                                const unsigned short* __restrict__ cT,
                                                float* __restrict__ out){
  int bx = blockIdx.x;            // N tile (128 cols of b)
  int by = blockIdx.y;            // M tile (128 rows), 8 tiles
  int tid = threadIdx.x;
  int wave = tid >> 6, lane = tid & 63;
  int wy = wave >> 1, wx = wave & 1;
  int lane15 = lane & 15, quad = lane >> 4;
  int rowBase = by*128 + wy*64;
  int colBase = bx*128 + wx*64;
  const bf16x8* Ap8 = (const bf16x8*)A2;   // 16B units: (c*1024 + row)
  const short* Bp = (const short*)cT;      // [col][k]

  f32x4 acc[4][4];
  #pragma unroll
  for (int i = 0; i < 4; ++i)
    #pragma unroll
    for (int j = 0; j < 4; ++j)
      acc[i][j] = (f32x4){0.f, 0.f, 0.f, 0.f};

  #pragma unroll 4
  for (int k0 = 0; k0 < NS; k0 += 32){
    bf16x8 a[4], b[4];
    int c = (k0 >> 3) + quad;
    #pragma unroll
    for (int mi = 0; mi < 4; ++mi)
      a[mi] = Ap8[(size_t)c*1024 + rowBase + mi*16 + lane15];
    #pragma unroll
    for (int ni = 0; ni < 4; ++ni)
      b[ni] = *(const bf16x8*)(Bp + (size_t)(colBase + ni*16 + lane15)*NS + k0 + quad*8);
    #pragma unroll
    for (int mi = 0; mi < 4; ++mi)
      #pragma unroll
      for (int ni = 0; ni < 4; ++ni)
        acc[mi][ni] = __builtin_amdgcn_mfma_f32_16x16x32_bf16(a[mi], b[ni], acc[mi][ni], 0, 0, 0);
  }

  float sign = (by & 2) ? -1.f : 1.f;
  #pragma unroll
  for (int ni = 0; ni < 4; ++ni){
    float cs = 0.f;
    #pragma unroll
    for (int mi = 0; mi < 4; ++mi)
      #pragma unroll
      for (int r = 0; r < 4; ++r)
        cs += acc[mi][ni][r] * acc[mi][ni][r];
    cs += __shfl_xor(cs, 16);
    cs += __shfl_xor(cs, 32);
    if (quad == 0)
      atomicAdd(out + colBase + ni*16 + lane15, sign * cs);
  }
}

extern "C" void kernel_launch(void* const* d_in, const int* in_sizes, int n_in,
                              void* d_out, int out_size, void* d_ws, size_t ws_size,
                              hipStream_t stream) {
  const float* adds    = (const float*)d_in[0];
  const float* params  = (const float*)d_in[1];
  const float* weights = (const float*)d_in[2];
  const float* params2 = (const float*)d_in[3];
  float* out = (float*)d_out;
  int B = in_sizes[0] / NQ;   // 8192

  unsigned short* A2 = (unsigned short*)d_ws;        // 1024*512 bf16 = 1 MB (c-blocked)
  unsigned short* cT = A2 + (size_t)M2 * NS;         // B*512 bf16 = 8 MB

  int prepBlocks = (B * 64 + 511) / 512;             // 1024
  hipLaunchKernelGGL(sim_prep, dim3(NSIMB + prepBlocks), dim3(512), 0, stream,
                     params, weights, params2, adds, A2, cT, out, B);
  hipLaunchKernelGGL(gemm_out, dim3(B / 128, 8), dim3(256), 0, stream, A2, cT, out);
}